// Round 1
// baseline (5713.148 us; speedup 1.0000x reference)
//
#include <hip/hip_runtime.h>
#include <hip/hip_bf16.h>
#include <stdint.h>

#define NPT   16384   // N
#define BB    4
#define SS    1024    // NPOINT
#define KK    32      // NSAMPLE
#define RR    (BB*SS*KK) // 131072 rows
#define C1    67
#define O1    64
#define O3    128
#define EPSF  1e-5f
#define R2F   0.09f   // f32(0.09) — matches jnp weak-typed scalar promotion

// ---------------- FPS: one block per batch, coords in registers ----------------
__global__ __launch_bounds__(1024) void k_fps(const float* __restrict__ xyz,
                                              int* __restrict__ fps_idx) {
    const int b = blockIdx.x;
    const int tid = threadIdx.x;
    const int lane = tid & 63, wv = tid >> 6;
    const float* xb = xyz + (size_t)b * 3 * NPT;
    float px[16], py[16], pz[16], dist[16];
#pragma unroll
    for (int j = 0; j < 16; ++j) {
        int n = j * 1024 + tid;
        px[j] = xb[n]; py[j] = xb[NPT + n]; pz[j] = xb[2 * NPT + n];
        dist[j] = 1e10f;
    }
    __shared__ float s_bd[16];
    __shared__ int   s_bi[16];
    __shared__ int   s_far;
    int far = 0;
    for (int it = 0; it < SS; ++it) {
        if (tid == 0) fps_idx[b * SS + it] = far;
        float cx = xb[far], cy = xb[NPT + far], cz = xb[2 * NPT + far];
        float bd = -1.0f; int bi = 0x7fffffff;
#pragma unroll
        for (int j = 0; j < 16; ++j) {
            // exact reference arithmetic: (dx*dx + dy*dy) + dz*dz, no FMA
            float dx = __fsub_rn(px[j], cx);
            float dy = __fsub_rn(py[j], cy);
            float dz = __fsub_rn(pz[j], cz);
            float d = __fadd_rn(__fadd_rn(__fmul_rn(dx, dx), __fmul_rn(dy, dy)),
                                __fmul_rn(dz, dz));
            float dj = fminf(dist[j], d);
            dist[j] = dj;
            if (dj > bd) { bd = dj; bi = j * 1024 + tid; }  // strict > keeps lowest j
        }
        // wave argmax, tie -> lowest index (matches jnp.argmax first-occurrence)
#pragma unroll
        for (int off = 32; off >= 1; off >>= 1) {
            float od = __shfl_xor(bd, off);
            int   oi = __shfl_xor(bi, off);
            if (od > bd || (od == bd && oi < bi)) { bd = od; bi = oi; }
        }
        if (lane == 0) { s_bd[wv] = bd; s_bi[wv] = bi; }
        __syncthreads();
        if (tid == 0) {
            float fb = s_bd[0]; int fi = s_bi[0];
            for (int w = 1; w < 16; ++w) {
                if (s_bd[w] > fb || (s_bd[w] == fb && s_bi[w] < fi)) { fb = s_bd[w]; fi = s_bi[w]; }
            }
            s_far = fi;
        }
        __syncthreads();
        far = s_far;
    }
}

// ---------------- gather new_xyz: write output0 (B,3,S) + ws copy (b,s,3) ------
__global__ void k_newxyz(const float* __restrict__ xyz, const int* __restrict__ fps_idx,
                         float* __restrict__ out0, float* __restrict__ nxyz) {
    int g = blockIdx.x * blockDim.x + threadIdx.x;
    if (g >= BB * SS) return;
    int b = g / SS, s = g % SS;
    int id = fps_idx[g];
    const float* xb = xyz + (size_t)b * 3 * NPT;
#pragma unroll
    for (int c = 0; c < 3; ++c) {
        float v = xb[c * NPT + id];
        out0[(size_t)b * 3 * SS + c * SS + s] = v;
        nxyz[g * 3 + c] = v;
    }
}

// ---------------- ball query: thread per (b,s), ordered scan, early exit -------
__global__ void k_ball(const float* __restrict__ xyz, const float* __restrict__ nxyz,
                       int* __restrict__ ballidx) {
    int g = blockIdx.x * blockDim.x + threadIdx.x;
    if (g >= BB * SS) return;
    int b = g / SS;
    const float* xb = xyz + (size_t)b * 3 * NPT;
    float nx = nxyz[g * 3], ny = nxyz[g * 3 + 1], nz = nxyz[g * 3 + 2];
    int cnt = 0;
    int* out = ballidx + (size_t)g * KK;
    for (int n = 0; n < NPT; ++n) {
        float dx = __fsub_rn(nx, xb[n]);
        float dy = __fsub_rn(ny, xb[NPT + n]);
        float dz = __fsub_rn(nz, xb[2 * NPT + n]);
        float d = __fadd_rn(__fadd_rn(__fmul_rn(dx, dx), __fmul_rn(dy, dy)),
                            __fmul_rn(dz, dz));
        if (!(d > R2F)) {            // matches reference: excluded iff sqr > r^2
            out[cnt++] = n;
            if (cnt == KK) break;
        }
    }
    int first = out[0];              // at least the centroid itself is a hit
    for (int j = cnt; j < KK; ++j) out[j] = first;
}

// ---------------- layer1: fused gather + GEMM(67->64) + BN partial sums --------
__global__ __launch_bounds__(256) void k_gemm1(const float* __restrict__ xyz,
        const float* __restrict__ pts, const float* __restrict__ nxyz,
        const int* __restrict__ ballidx, const float* __restrict__ w,
        const float* __restrict__ bias, float* __restrict__ Y,
        float* __restrict__ sumP, float* __restrict__ sqP) {
    __shared__ float wlds[C1 * O1];   // [c][o]
    __shared__ float blds[O1];
    __shared__ float lsum[4][O1];
    __shared__ float lsq[4][O1];
    for (int i = threadIdx.x; i < C1 * O1; i += 256) {
        int c = i / O1, o = i % O1;
        wlds[i] = w[o * C1 + c];
    }
    if (threadIdx.x < O1) blds[threadIdx.x] = bias[threadIdx.x];
    __syncthreads();
    int r = blockIdx.x * 256 + threadIdx.x;
    int b = r >> 15;
    int g = r >> 5;                   // b*SS + s
    int id = ballidx[r];
    const float* xb = xyz + (size_t)b * 3 * NPT;
    const float* pb = pts + (size_t)b * 64 * NPT;
    float acc[O1];
#pragma unroll
    for (int o = 0; o < O1; ++o) acc[o] = blds[o];
#pragma unroll
    for (int c = 0; c < 3; ++c) {
        float xv = xb[c * NPT + id] - nxyz[g * 3 + c];
        const float* wr = &wlds[c * O1];
#pragma unroll
        for (int o = 0; o < O1; ++o) acc[o] = fmaf(xv, wr[o], acc[o]);
    }
    for (int c = 0; c < 64; ++c) {
        float xv = pb[(size_t)c * NPT + id];
        const float* wr = &wlds[(c + 3) * O1];
#pragma unroll
        for (int o = 0; o < O1; ++o) acc[o] = fmaf(xv, wr[o], acc[o]);
    }
    float* yr = Y + (size_t)r * O1;
#pragma unroll
    for (int o = 0; o < O1; ++o) yr[o] = acc[o];
    int lane = threadIdx.x & 63, wv = threadIdx.x >> 6;
#pragma unroll
    for (int o = 0; o < O1; ++o) {
        float v = acc[o], v2 = acc[o] * acc[o];
#pragma unroll
        for (int off = 1; off < 64; off <<= 1) { v += __shfl_xor(v, off); v2 += __shfl_xor(v2, off); }
        if (lane == 0) { lsum[wv][o] = v; lsq[wv][o] = v2; }
    }
    __syncthreads();
    if (threadIdx.x < O1) {
        int o = threadIdx.x;
        sumP[blockIdx.x * O1 + o] = lsum[0][o] + lsum[1][o] + lsum[2][o] + lsum[3][o];
        sqP[blockIdx.x * O1 + o]  = lsq[0][o] + lsq[1][o] + lsq[2][o] + lsq[3][o];
    }
}

// ---------------- generic GEMM. MODE 0: write Y + partials (layer2)
//                  MODE 1: partials only (layer3 pass A)
//                  MODE 2: normalize+relu+max32 -> out1 (layer3 pass B) ---------
template <int CIN, int COUT, int MODE>
__global__ __launch_bounds__(256) void k_gemm(const float* __restrict__ Yin,
        const float* __restrict__ w, const float* __restrict__ bias,
        float* __restrict__ Yout, float* __restrict__ sumP, float* __restrict__ sqP,
        const float* __restrict__ scale, const float* __restrict__ shift,
        float* __restrict__ out1) {
    __shared__ float wlds[CIN * COUT];   // [c][o]
    __shared__ float blds[COUT];
    __shared__ float lsum[4][COUT];
    __shared__ float lsq[4][COUT];
    for (int i = threadIdx.x; i < CIN * COUT; i += 256) {
        int c = i / COUT, o = i % COUT;
        wlds[i] = w[o * CIN + c];
    }
    for (int i = threadIdx.x; i < COUT; i += 256) blds[i] = bias[i];
    __syncthreads();
    int r = blockIdx.x * 256 + threadIdx.x;
    float acc[COUT];
#pragma unroll
    for (int o = 0; o < COUT; ++o) acc[o] = blds[o];
    const float* row = Yin + (size_t)r * CIN;
#pragma unroll 4
    for (int c = 0; c < CIN; ++c) {
        float xv = row[c];
        const float* wr = &wlds[c * COUT];
#pragma unroll
        for (int o = 0; o < COUT; ++o) acc[o] = fmaf(xv, wr[o], acc[o]);
    }
    if (MODE == 0) {
        float* yr = Yout + (size_t)r * COUT;
#pragma unroll
        for (int o = 0; o < COUT; ++o) yr[o] = acc[o];
    }
    if (MODE <= 1) {
        int lane = threadIdx.x & 63, wv = threadIdx.x >> 6;
#pragma unroll
        for (int o = 0; o < COUT; ++o) {
            float v = acc[o], v2 = acc[o] * acc[o];
#pragma unroll
            for (int off = 1; off < 64; off <<= 1) { v += __shfl_xor(v, off); v2 += __shfl_xor(v2, off); }
            if (lane == 0) { lsum[wv][o] = v; lsq[wv][o] = v2; }
        }
        __syncthreads();
        if (threadIdx.x < COUT) {
            int o = threadIdx.x;
            sumP[blockIdx.x * COUT + o] = lsum[0][o] + lsum[1][o] + lsum[2][o] + lsum[3][o];
            sqP[blockIdx.x * COUT + o]  = lsq[0][o] + lsq[1][o] + lsq[2][o] + lsq[3][o];
        }
    } else {
        int b = r >> 15, s = (r >> 5) & (SS - 1);
#pragma unroll
        for (int o = 0; o < COUT; ++o) {
            float v = fmaxf(fmaf(acc[o], scale[o], shift[o]), 0.0f);
#pragma unroll
            for (int off = 1; off < 32; off <<= 1) v = fmaxf(v, __shfl_xor(v, off));
            if ((threadIdx.x & 31) == 0) out1[(size_t)b * O3 * SS + o * SS + s] = v;
        }
    }
}

// ---------------- finalize BN stats: partials -> scale/shift -------------------
template <int COUT, int NB>
__global__ void k_finalize(const float* __restrict__ sumP, const float* __restrict__ sqP,
                           const float* __restrict__ g, const float* __restrict__ beta,
                           float* __restrict__ scale, float* __restrict__ shift) {
    int o = threadIdx.x;
    if (o >= COUT) return;
    float s = 0.f, q = 0.f;
    for (int bk = 0; bk < NB; ++bk) { s += sumP[bk * COUT + o]; q += sqP[bk * COUT + o]; }
    const float inv = 1.0f / (float)RR;
    float mean = s * inv;
    float var = q * inv - mean * mean;
    float sc = g[o] * rsqrtf(var + EPSF);
    scale[o] = sc;
    shift[o] = beta[o] - mean * sc;
}

// ---------------- in-place normalize + relu (layers 1,2) -----------------------
__global__ void k_norm(float* __restrict__ Y, const float* __restrict__ scale,
                       const float* __restrict__ shift, int total4, int coutMask) {
    int i = blockIdx.x * blockDim.x + threadIdx.x;
    if (i >= total4) return;
    float4 v = reinterpret_cast<float4*>(Y)[i];
    int o = (i << 2) & coutMask;
    float4 sc = *reinterpret_cast<const float4*>(scale + o);
    float4 sh = *reinterpret_cast<const float4*>(shift + o);
    v.x = fmaxf(fmaf(v.x, sc.x, sh.x), 0.0f);
    v.y = fmaxf(fmaf(v.y, sc.y, sh.y), 0.0f);
    v.z = fmaxf(fmaf(v.z, sc.z, sh.z), 0.0f);
    v.w = fmaxf(fmaf(v.w, sc.w, sh.w), 0.0f);
    reinterpret_cast<float4*>(Y)[i] = v;
}

extern "C" void kernel_launch(void* const* d_in, const int* in_sizes, int n_in,
                              void* d_out, int out_size, void* d_ws, size_t ws_size,
                              hipStream_t stream) {
    const float* xyz = (const float*)d_in[0];
    const float* pts = (const float*)d_in[1];
    const float* w1  = (const float*)d_in[2];
    const float* b1  = (const float*)d_in[3];
    const float* g1  = (const float*)d_in[4];
    const float* bt1 = (const float*)d_in[5];
    const float* w2  = (const float*)d_in[6];
    const float* b2  = (const float*)d_in[7];
    const float* g2  = (const float*)d_in[8];
    const float* bt2 = (const float*)d_in[9];
    const float* w3  = (const float*)d_in[10];
    const float* b3  = (const float*)d_in[11];
    const float* g3  = (const float*)d_in[12];
    const float* bt3 = (const float*)d_in[13];
    float* out0 = (float*)d_out;                 // (B,3,S)
    float* out1 = out0 + BB * 3 * SS;            // (B,128,S)

    char* wsb = (char*)d_ws;
    size_t off = 0;
    auto alloc = [&](size_t bytes) {
        char* p = wsb + off;
        off += (bytes + 255) & ~(size_t)255;
        return p;
    };
    int*   fps_idx = (int*)alloc((size_t)BB * SS * 4);
    int*   ballidx = (int*)alloc((size_t)RR * 4);
    float* nxyz    = (float*)alloc((size_t)BB * SS * 3 * 4);
    float* sumP    = (float*)alloc((size_t)512 * 128 * 4);
    float* sqP     = (float*)alloc((size_t)512 * 128 * 4);
    float* scale   = (float*)alloc(128 * 4);
    float* shift   = (float*)alloc(128 * 4);
    float* Y1      = (float*)alloc((size_t)RR * 64 * 4);
    float* Y2      = (float*)alloc((size_t)RR * 64 * 4);

    k_fps<<<BB, 1024, 0, stream>>>(xyz, fps_idx);
    k_newxyz<<<16, 256, 0, stream>>>(xyz, fps_idx, out0, nxyz);
    k_ball<<<16, 256, 0, stream>>>(xyz, nxyz, ballidx);

    k_gemm1<<<512, 256, 0, stream>>>(xyz, pts, nxyz, ballidx, w1, b1, Y1, sumP, sqP);
    k_finalize<64, 512><<<1, 64, 0, stream>>>(sumP, sqP, g1, bt1, scale, shift);
    k_norm<<<(RR * 64 / 4 + 255) / 256, 256, 0, stream>>>(Y1, scale, shift, RR * 64 / 4, 63);

    k_gemm<64, 64, 0><<<512, 256, 0, stream>>>(Y1, w2, b2, Y2, sumP, sqP, nullptr, nullptr, nullptr);
    k_finalize<64, 512><<<1, 64, 0, stream>>>(sumP, sqP, g2, bt2, scale, shift);
    k_norm<<<(RR * 64 / 4 + 255) / 256, 256, 0, stream>>>(Y2, scale, shift, RR * 64 / 4, 63);

    k_gemm<64, 128, 1><<<512, 256, 0, stream>>>(Y2, w3, b3, nullptr, sumP, sqP, nullptr, nullptr, nullptr);
    k_finalize<128, 512><<<1, 128, 0, stream>>>(sumP, sqP, g3, bt3, scale, shift);
    k_gemm<64, 128, 2><<<512, 256, 0, stream>>>(Y2, w3, b3, nullptr, nullptr, nullptr, scale, shift, out1);
}